// Round 1
// baseline (448.510 us; speedup 1.0000x reference)
//
#include <hip/hip_runtime.h>
#include <hip/hip_bf16.h>

#define NB 32
#define SEQ 1024
#define DIM 64

// ---------------- Kernel 1: fused QKV projection ----------------
// q = (x @ Wq^T) * 1/sqrt(D)  (scale folded here), k = x @ Wk^T, v = x @ Wv^T
// Block: 256 threads handles ROWS_PB rows. W stored transposed+padded in LDS
// so per-lane reads wt[i][h] hit distinct banks (2-way max = free).
#define ROWS_PB 32
__global__ __launch_bounds__(256) void qkv_proj(
    const float* __restrict__ x, const float* __restrict__ Wq,
    const float* __restrict__ Wk, const float* __restrict__ Wv,
    float* __restrict__ q, float* __restrict__ k, float* __restrict__ v)
{
    __shared__ float xs[ROWS_PB][DIM];
    __shared__ float wq[DIM][DIM + 1];
    __shared__ float wk[DIM][DIM + 1];
    __shared__ float wv[DIM][DIM + 1];
    const int tid = threadIdx.x;
    const long row0 = (long)blockIdx.x * ROWS_PB;

    for (int idx = tid; idx < ROWS_PB * DIM; idx += 256)
        ((float*)xs)[idx] = x[row0 * DIM + idx];
    for (int idx = tid; idx < DIM * DIM; idx += 256) {
        const int h = idx >> 6, i = idx & 63;
        wq[i][h] = Wq[idx];
        wk[i][h] = Wk[idx];
        wv[i][h] = Wv[idx];
    }
    __syncthreads();

    const int h = tid & 63;
    const int rg = tid >> 6;  // wave id: rows partitioned across 4 waves
    #pragma unroll
    for (int j = 0; j < ROWS_PB / 4; ++j) {
        const int r = rg * (ROWS_PB / 4) + j;
        float aq = 0.f, ak = 0.f, av = 0.f;
        #pragma unroll
        for (int i = 0; i < DIM; ++i) {
            const float xv = xs[r][i];      // same addr across lanes: broadcast
            aq += xv * wq[i][h];            // banks spread by h: conflict-free
            ak += xv * wk[i][h];
            av += xv * wv[i][h];
        }
        const long o = (row0 + r) * DIM + h;  // lanes h consecutive: coalesced
        q[o] = aq * 0.125f;  // 1/sqrt(64)
        k[o] = ak;
        v[o] = av;
    }
}

// ---------------- Kernel 2: flash-style causal attention ----------------
// Block = (batch, 64-row q-tile), 256 threads = 4 waves.
// Thread mapping: qr = tid>>2 (q row in tile), sub = tid&3 (16-dim slice).
// K/V tiles (64x64 fp32, 16KB each) staged in LDS. Online softmax streaming
// per k element; 4-lane shfl_xor reduce completes each dot product.
#define BQ 64
#define KT 64
__global__ __launch_bounds__(256) void attn(
    const float* __restrict__ q, const float* __restrict__ k,
    const float* __restrict__ v, float* __restrict__ out)
{
    __shared__ float ks[KT][DIM];
    __shared__ float vs[KT][DIM];
    const int tid = threadIdx.x;
    const int b  = blockIdx.x >> 4;   // SEQ/BQ = 16 q-tiles per batch
    const int qt = blockIdx.x & 15;
    const int q0 = qt * BQ;
    const int qr  = tid >> 2;
    const int sub = tid & 3;
    const int qrow = q0 + qr;         // absolute query index

    // load this thread's 16-dim slice of its q row (scale already folded)
    const float* qp = q + ((size_t)(b * SEQ + qrow)) * DIM + sub * 16;
    float qreg[16];
    #pragma unroll
    for (int i4 = 0; i4 < 4; ++i4) {
        const float4 t = ((const float4*)qp)[i4];
        qreg[i4 * 4 + 0] = t.x; qreg[i4 * 4 + 1] = t.y;
        qreg[i4 * 4 + 2] = t.z; qreg[i4 * 4 + 3] = t.w;
    }

    float acc[16];
    #pragma unroll
    for (int i = 0; i < 16; ++i) acc[i] = 0.f;
    float m = -1e30f, l = 0.f;

    const int ntiles = qt + 1;  // causal: only tiles with k0 <= q0+BQ-1
    for (int t = 0; t < ntiles; ++t) {
        const int k0 = t * KT;
        const float4* kg = (const float4*)(k + ((size_t)(b * SEQ + k0)) * DIM);
        const float4* vg = (const float4*)(v + ((size_t)(b * SEQ + k0)) * DIM);
        for (int idx = tid; idx < KT * DIM / 4; idx += 256) {
            ((float4*)ks)[idx] = kg[idx];
            ((float4*)vs)[idx] = vg[idx];
        }
        __syncthreads();

        const int kmax = min(KT, qrow - k0 + 1);  // causal bound in this tile
        for (int kc = 0; kc < kmax; ++kc) {
            // dot(q_row, k_row): 16 dims per lane + 4-lane butterfly reduce
            float p = 0.f;
            const float* krow = &ks[kc][sub * 16];
            #pragma unroll
            for (int i = 0; i < 16; ++i) p += qreg[i] * krow[i];
            p += __shfl_xor(p, 1);
            p += __shfl_xor(p, 2);
            // online softmax update (all 4 sub-lanes identical)
            const float mnew = fmaxf(m, p);
            const float scale = __expf(m - mnew);
            const float pe = __expf(p - mnew);
            l = l * scale + pe;
            m = mnew;
            const float* vrow = &vs[kc][sub * 16];
            #pragma unroll
            for (int i = 0; i < 16; ++i) acc[i] = acc[i] * scale + pe * vrow[i];
        }
        __syncthreads();
    }

    const float inv = 1.0f / l;
    float* op = out + ((size_t)(b * SEQ + qrow)) * DIM + sub * 16;
    #pragma unroll
    for (int i4 = 0; i4 < 4; ++i4) {
        float4 t;
        t.x = acc[i4 * 4 + 0] * inv; t.y = acc[i4 * 4 + 1] * inv;
        t.z = acc[i4 * 4 + 2] * inv; t.w = acc[i4 * 4 + 3] * inv;
        ((float4*)op)[i4] = t;
    }
}

extern "C" void kernel_launch(void* const* d_in, const int* in_sizes, int n_in,
                              void* d_out, int out_size, void* d_ws, size_t ws_size,
                              hipStream_t stream) {
    const float* x  = (const float*)d_in[0];
    const float* Wq = (const float*)d_in[1];
    const float* Wk = (const float*)d_in[2];
    const float* Wv = (const float*)d_in[3];
    float* outp = (float*)d_out;

    // workspace layout: q | k | v, each NB*SEQ*DIM fp32 (8 MB each, 24 MB total)
    float* qw = (float*)d_ws;
    float* kw = qw + (size_t)NB * SEQ * DIM;
    float* vw = kw + (size_t)NB * SEQ * DIM;

    qkv_proj<<<NB * SEQ / ROWS_PB, 256, 0, stream>>>(x, Wq, Wk, Wv, qw, kw, vw);
    attn<<<NB * (SEQ / BQ), 256, 0, stream>>>(qw, kw, vw, outp);
}

// Round 2
// 59.084 us; speedup vs baseline: 7.5911x; 7.5911x over previous
//
#include <hip/hip_runtime.h>
#include <hip/hip_bf16.h>

#define NB 32
#define SEQ 1024
#define DIM 64
#define LDP 72   // padded LDS row stride in bf16 elems: 144 B (16B-aligned, banks spread)

typedef __attribute__((ext_vector_type(8))) short bf16x8;
typedef __attribute__((ext_vector_type(8))) unsigned short ushort8;
typedef __attribute__((ext_vector_type(4))) float f32x4;

#define MFMA16 __builtin_amdgcn_mfma_f32_16x16x32_bf16

__device__ __forceinline__ unsigned short f2bf(float f) {
    union { float f; unsigned u; } c; c.f = f;
    return (unsigned short)((c.u + 0x7FFFu + ((c.u >> 16) & 1u)) >> 16);  // RNE
}

// ---------------- Kernel 1: QKV projection (bf16 MFMA) ----------------
// Writes q (scaled by 1/8, bf16 [B,S,D]), k (bf16 [B,S,D]), vT (bf16 [B,D,S]).
__global__ __launch_bounds__(256) void qkv_proj(
    const float* __restrict__ x, const float* __restrict__ Wq,
    const float* __restrict__ Wk, const float* __restrict__ Wv,
    unsigned short* __restrict__ qg, unsigned short* __restrict__ kg,
    unsigned short* __restrict__ vtg)
{
    __shared__ unsigned short xs[64 * LDP];
    __shared__ unsigned short ws[3][64 * LDP];
    __shared__ unsigned short vt[64 * LDP];

    const int tid = threadIdx.x;
    const int w = tid >> 6, lane = tid & 63;
    const int l15 = lane & 15, l4 = lane >> 4;
    const size_t row0 = (size_t)blockIdx.x * 64;

    {   // stage x rows + all three W matrices as bf16 (rows padded)
        const int r = tid >> 2, c = (tid & 3) * 16;
        const float* xsrc = x + (row0 + r) * DIM + c;
        const float* w0 = Wq + r * DIM + c;
        const float* w1 = Wk + r * DIM + c;
        const float* w2 = Wv + r * DIM + c;
        ushort8 t0, t1;
        #pragma unroll
        for (int i = 0; i < 8; ++i) { t0[i] = f2bf(xsrc[i]); t1[i] = f2bf(xsrc[i + 8]); }
        *(ushort8*)&xs[r * LDP + c] = t0; *(ushort8*)&xs[r * LDP + c + 8] = t1;
        #pragma unroll
        for (int i = 0; i < 8; ++i) { t0[i] = f2bf(w0[i]); t1[i] = f2bf(w0[i + 8]); }
        *(ushort8*)&ws[0][r * LDP + c] = t0; *(ushort8*)&ws[0][r * LDP + c + 8] = t1;
        #pragma unroll
        for (int i = 0; i < 8; ++i) { t0[i] = f2bf(w1[i]); t1[i] = f2bf(w1[i + 8]); }
        *(ushort8*)&ws[1][r * LDP + c] = t0; *(ushort8*)&ws[1][r * LDP + c + 8] = t1;
        #pragma unroll
        for (int i = 0; i < 8; ++i) { t0[i] = f2bf(w2[i]); t1[i] = f2bf(w2[i + 8]); }
        *(ushort8*)&ws[2][r * LDP + c] = t0; *(ushort8*)&ws[2][r * LDP + c + 8] = t1;
    }
    __syncthreads();

    // A-frags: wave w owns output rows w*16..w*16+15
    const bf16x8 xa0 = *(const bf16x8*)&xs[(w * 16 + l15) * LDP + l4 * 8];
    const bf16x8 xa1 = *(const bf16x8*)&xs[(w * 16 + l15) * LDP + 32 + l4 * 8];

    #pragma unroll
    for (int m = 0; m < 3; ++m) {
        #pragma unroll
        for (int nb = 0; nb < 4; ++nb) {
            const bf16x8 b0 = *(const bf16x8*)&ws[m][(nb * 16 + l15) * LDP + l4 * 8];
            const bf16x8 b1 = *(const bf16x8*)&ws[m][(nb * 16 + l15) * LDP + 32 + l4 * 8];
            f32x4 a = {0.f, 0.f, 0.f, 0.f};
            a = MFMA16(xa0, b0, a, 0, 0, 0);
            a = MFMA16(xa1, b1, a, 0, 0, 0);
            #pragma unroll
            for (int r = 0; r < 4; ++r) {
                const int row = w * 16 + l4 * 4 + r, col = nb * 16 + l15;
                if (m == 0)      qg[(row0 + row) * DIM + col] = f2bf(a[r] * 0.125f);
                else if (m == 1) kg[(row0 + row) * DIM + col] = f2bf(a[r]);
                else             vt[col * LDP + row] = f2bf(a[r]);  // transpose v in LDS
            }
        }
    }
    __syncthreads();
    {   // coalesced write of vT tile: vT[b][d][s0..s0+63]
        const int r = tid >> 2, c = (tid & 3) * 16;
        const size_t b = row0 >> 10; const int s0 = (int)(row0 & 1023);
        unsigned short* dst = vtg + (b * 64 + r) * SEQ + s0 + c;
        *(ushort8*)dst       = *(const ushort8*)&vt[r * LDP + c];
        *(ushort8*)(dst + 8) = *(const ushort8*)&vt[r * LDP + c + 8];
    }
}

// ---------------- Kernel 2: flash attention (bf16 MFMA) ----------------
// Block = (batch, 64-row q-tile), 4 waves; wave w owns q rows q0+w*16..+15.
// Per 64-k tile: QK^T (8 mfma) -> tile softmax (one rescale) -> PV (8 mfma).
__global__ __launch_bounds__(256) void attn(
    const unsigned short* __restrict__ qg, const unsigned short* __restrict__ kg,
    const unsigned short* __restrict__ vtg, float* __restrict__ out)
{
    __shared__ unsigned short Ks[64 * LDP];
    __shared__ unsigned short Vt[64 * LDP];
    __shared__ unsigned short Ps[4][16 * LDP];   // wave-private P tiles

    const int tid = threadIdx.x;
    const int w = tid >> 6, lane = tid & 63;
    const int l15 = lane & 15, l4 = lane >> 4;

    const int bx = blockIdx.x;
    const int b = bx >> 4;
    const int t = bx & 15;
    const int qt = (t & 1) ? (t >> 1) : (15 - (t >> 1));  // pair heavy+light tiles
    const int q0 = qt * 64;

    // Q A-frags held in registers for the whole k-loop (scale pre-folded)
    const unsigned short* qp = qg + ((size_t)(b * SEQ + q0 + w * 16 + l15)) * DIM + l4 * 8;
    const bf16x8 qf0 = *(const bf16x8*)qp;
    const bf16x8 qf1 = *(const bf16x8*)(qp + 32);

    f32x4 acc[4] = {};
    float m_run[4], l_run[4];
    #pragma unroll
    for (int r = 0; r < 4; ++r) { m_run[r] = -1e30f; l_run[r] = 0.f; }

    const int ntiles = qt + 1;
    for (int tt = 0; tt < ntiles; ++tt) {
        const int k0 = tt * 64;
        {   // stage K tile + V^T tile (bf16, padded rows)
            const int r = tid >> 2, c = (tid & 3) * 16;
            const unsigned short* ksrc = kg + ((size_t)(b * SEQ + k0 + r)) * DIM + c;
            *(ushort8*)&Ks[r * LDP + c]     = *(const ushort8*)ksrc;
            *(ushort8*)&Ks[r * LDP + c + 8] = *(const ushort8*)(ksrc + 8);
            const unsigned short* vsrc = vtg + ((size_t)(b * 64 + r)) * SEQ + k0 + c;
            *(ushort8*)&Vt[r * LDP + c]     = *(const ushort8*)vsrc;
            *(ushort8*)&Vt[r * LDP + c + 8] = *(const ushort8*)(vsrc + 8);
        }
        __syncthreads();

        // S = Q . K^T : 4 col-blocks x (2 k-chunks)
        f32x4 s[4];
        #pragma unroll
        for (int nb = 0; nb < 4; ++nb) {
            const bf16x8 kf0 = *(const bf16x8*)&Ks[(nb * 16 + l15) * LDP + l4 * 8];
            const bf16x8 kf1 = *(const bf16x8*)&Ks[(nb * 16 + l15) * LDP + 32 + l4 * 8];
            f32x4 sv = {0.f, 0.f, 0.f, 0.f};
            sv = MFMA16(qf0, kf0, sv, 0, 0, 0);
            sv = MFMA16(qf1, kf1, sv, 0, 0, 0);
            s[nb] = sv;
        }

        if (tt == qt) {  // causal mask, diagonal tile only
            #pragma unroll
            for (int nb = 0; nb < 4; ++nb)
                #pragma unroll
                for (int r = 0; r < 4; ++r) {
                    const int i = q0 + w * 16 + l4 * 4 + r;
                    const int j = k0 + nb * 16 + l15;
                    if (j > i) s[nb][r] = -1e30f;
                }
        }

        // tile softmax: row = l4*4+r, spread over 16 lanes (l15 = col)
        float pmax[4], psum[4], scale[4];
        #pragma unroll
        for (int r = 0; r < 4; ++r)
            pmax[r] = fmaxf(fmaxf(s[0][r], s[1][r]), fmaxf(s[2][r], s[3][r]));
        #pragma unroll
        for (int off = 1; off < 16; off <<= 1)
            #pragma unroll
            for (int r = 0; r < 4; ++r)
                pmax[r] = fmaxf(pmax[r], __shfl_xor(pmax[r], off));
        #pragma unroll
        for (int r = 0; r < 4; ++r) {
            const float mn = fmaxf(m_run[r], pmax[r]);
            scale[r] = __expf(m_run[r] - mn);
            m_run[r] = mn;
        }
        #pragma unroll
        for (int nb = 0; nb < 4; ++nb)
            #pragma unroll
            for (int r = 0; r < 4; ++r)
                s[nb][r] = __expf(s[nb][r] - m_run[r]);
        #pragma unroll
        for (int r = 0; r < 4; ++r)
            psum[r] = (s[0][r] + s[1][r]) + (s[2][r] + s[3][r]);
        #pragma unroll
        for (int off = 1; off < 16; off <<= 1)
            #pragma unroll
            for (int r = 0; r < 4; ++r)
                psum[r] += __shfl_xor(psum[r], off);
        #pragma unroll
        for (int r = 0; r < 4; ++r) {
            l_run[r] = l_run[r] * scale[r] + psum[r];
            acc[0][r] *= scale[r]; acc[1][r] *= scale[r];
            acc[2][r] *= scale[r]; acc[3][r] *= scale[r];
        }

        // P: C-layout -> bf16 -> wave-private LDS (A-layout readback)
        #pragma unroll
        for (int nb = 0; nb < 4; ++nb)
            #pragma unroll
            for (int r = 0; r < 4; ++r)
                Ps[w][(l4 * 4 + r) * LDP + nb * 16 + l15] = f2bf(s[nb][r]);
        __syncthreads();

        // O += P . V  (A = P from LDS, B = V^T rows)
        const bf16x8 pa0 = *(const bf16x8*)&Ps[w][l15 * LDP + l4 * 8];
        const bf16x8 pa1 = *(const bf16x8*)&Ps[w][l15 * LDP + 32 + l4 * 8];
        #pragma unroll
        for (int nb = 0; nb < 4; ++nb) {
            const bf16x8 vb0 = *(const bf16x8*)&Vt[(nb * 16 + l15) * LDP + l4 * 8];
            const bf16x8 vb1 = *(const bf16x8*)&Vt[(nb * 16 + l15) * LDP + 32 + l4 * 8];
            acc[nb] = MFMA16(pa0, vb0, acc[nb], 0, 0, 0);
            acc[nb] = MFMA16(pa1, vb1, acc[nb], 0, 0, 0);
        }
        __syncthreads();  // protect Ks/Vt/Ps before next stage
    }

    float inv[4];
    #pragma unroll
    for (int r = 0; r < 4; ++r) inv[r] = 1.0f / l_run[r];
    #pragma unroll
    for (int nb = 0; nb < 4; ++nb)
        #pragma unroll
        for (int r = 0; r < 4; ++r) {
            const size_t row = (size_t)(b * SEQ + q0 + w * 16 + l4 * 4 + r);
            out[row * DIM + nb * 16 + l15] = acc[nb][r] * inv[r];
        }
}

extern "C" void kernel_launch(void* const* d_in, const int* in_sizes, int n_in,
                              void* d_out, int out_size, void* d_ws, size_t ws_size,
                              hipStream_t stream) {
    const float* x  = (const float*)d_in[0];
    const float* Wq = (const float*)d_in[1];
    const float* Wk = (const float*)d_in[2];
    const float* Wv = (const float*)d_in[3];
    float* outp = (float*)d_out;

    // workspace: q | k | vT, each NB*SEQ*DIM bf16 (4 MB each)
    unsigned short* qw  = (unsigned short*)d_ws;
    unsigned short* kw  = qw + (size_t)NB * SEQ * DIM;
    unsigned short* vtw = kw + (size_t)NB * SEQ * DIM;

    qkv_proj<<<NB * SEQ / 64, 256, 0, stream>>>(x, Wq, Wk, Wv, qw, kw, vtw);
    attn<<<NB * (SEQ / 64), 256, 0, stream>>>(qw, kw, vtw, outp);
}

// Round 3
// 40.201 us; speedup vs baseline: 11.1567x; 1.4697x over previous
//
#include <hip/hip_runtime.h>
#include <hip/hip_bf16.h>

#define NB 32
#define SEQ 1024
#define DIM 64
#define LDP 72   // padded LDS row stride (bf16 elems): 144 B, 16B-aligned

typedef __attribute__((ext_vector_type(8))) short bf16x8;
typedef __attribute__((ext_vector_type(4))) float f32x4;

#define MFMA16 __builtin_amdgcn_mfma_f32_16x16x32_bf16

__device__ __forceinline__ unsigned short f2bf(float f) {
    union { float f; unsigned u; } c; c.f = f;
    return (unsigned short)((c.u + 0x7FFFu + ((c.u >> 16) & 1u)) >> 16);  // RNE
}
__device__ __forceinline__ unsigned pk2(float a, float b) {
    return (unsigned)f2bf(a) | ((unsigned)f2bf(b) << 16);
}
__device__ __forceinline__ bf16x8 cvt8(float4 a, float4 b) {
    bf16x8 r;
    r[0] = (short)f2bf(a.x); r[1] = (short)f2bf(a.y);
    r[2] = (short)f2bf(a.z); r[3] = (short)f2bf(a.w);
    r[4] = (short)f2bf(b.x); r[5] = (short)f2bf(b.y);
    r[6] = (short)f2bf(b.z); r[7] = (short)f2bf(b.w);
    return r;
}

// ---------------- Kernel 1: QKV projection (bf16 MFMA) ----------------
// q (x1/8, bf16 [B,S,D]), k (bf16 [B,S,D]), vT (bf16 [B,D,S]).
// x A-frags loaded straight from global (no LDS round-trip); W staged in LDS.
__global__ __launch_bounds__(256) void qkv_proj(
    const float* __restrict__ x, const float* __restrict__ Wq,
    const float* __restrict__ Wk, const float* __restrict__ Wv,
    unsigned short* __restrict__ qg, unsigned short* __restrict__ kg,
    unsigned short* __restrict__ vtg)
{
    __shared__ unsigned short ws[3][64 * LDP];
    __shared__ unsigned short vt[64 * LDP];
    const int tid = threadIdx.x;
    const int w = tid >> 6, lane = tid & 63;
    const int l15 = lane & 15, l4 = lane >> 4;
    const size_t row0 = (size_t)blockIdx.x * 64;

    {   // stage W matrices as bf16 (padded rows)
        const int r = tid >> 2, c = (tid & 3) * 16;
        const float* srcs[3] = {Wq, Wk, Wv};
        #pragma unroll
        for (int m = 0; m < 3; ++m) {
            const float* s = srcs[m] + r * DIM + c;
            const float4 f0 = ((const float4*)s)[0], f1 = ((const float4*)s)[1];
            const float4 f2 = ((const float4*)s)[2], f3 = ((const float4*)s)[3];
            *(bf16x8*)&ws[m][r * LDP + c]     = cvt8(f0, f1);
            *(bf16x8*)&ws[m][r * LDP + c + 8] = cvt8(f2, f3);
        }
    }
    // x A-frags direct from global: row = row0 + w*16 + l15, d = l4*8..
    const float* xp = x + (row0 + w * 16 + l15) * DIM + l4 * 8;
    const float4 x0 = ((const float4*)xp)[0];
    const float4 x1 = ((const float4*)xp)[1];
    const float4 x2 = ((const float4*)(xp + 32))[0];
    const float4 x3 = ((const float4*)(xp + 32))[1];
    const bf16x8 xa0 = cvt8(x0, x1), xa1 = cvt8(x2, x3);
    __syncthreads();

    #pragma unroll
    for (int m = 0; m < 3; ++m) {
        #pragma unroll
        for (int nb = 0; nb < 4; ++nb) {
            const bf16x8 b0 = *(const bf16x8*)&ws[m][(nb * 16 + l15) * LDP + l4 * 8];
            const bf16x8 b1 = *(const bf16x8*)&ws[m][(nb * 16 + l15) * LDP + 32 + l4 * 8];
            f32x4 a = {0.f, 0.f, 0.f, 0.f};
            a = MFMA16(xa0, b0, a, 0, 0, 0);
            a = MFMA16(xa1, b1, a, 0, 0, 0);
            #pragma unroll
            for (int r = 0; r < 4; ++r) {
                const int orow = w * 16 + l4 * 4 + r, ocol = nb * 16 + l15;
                if (m == 0)      qg[(row0 + orow) * DIM + ocol] = f2bf(a[r] * 0.125f);
                else if (m == 1) kg[(row0 + orow) * DIM + ocol] = f2bf(a[r]);
                else             vt[ocol * LDP + orow] = f2bf(a[r]);  // transpose v
            }
        }
    }
    __syncthreads();
    {   // coalesced vT tile store: vT[b][d][s0..s0+63]
        const int r = tid >> 2, c = (tid & 3) * 16;
        const size_t b = row0 >> 10; const int s0 = (int)(row0 & 1023);
        unsigned short* dst = vtg + (b * 64 + r) * SEQ + s0 + c;
        *(bf16x8*)dst       = *(const bf16x8*)&vt[r * LDP + c];
        *(bf16x8*)(dst + 8) = *(const bf16x8*)&vt[r * LDP + c + 8];
    }
}

// ---------------- Kernel 2: flash attention (bf16 MFMA, dbuf, swapped QK) ----
// Block = (batch, 64-row q-tile), 4 waves; wave w owns q rows q0+w*16..+15.
// S^T = mfma(K,Q): lane col (l15) = its own q-row -> 2-shfl softmax, packed
// b64 P writes. K/V double-buffered; next-tile loads issued before compute,
// LDS writes after PV; ONE barrier per tile.
__global__ __launch_bounds__(256) void attn(
    const unsigned short* __restrict__ qg, const unsigned short* __restrict__ kg,
    const unsigned short* __restrict__ vtg, float* __restrict__ out)
{
    __shared__ unsigned short Ks[2][64 * LDP];
    __shared__ unsigned short Vs[2][64 * LDP];
    __shared__ unsigned short Ps[4][16 * LDP];

    const int tid = threadIdx.x;
    const int w = tid >> 6, lane = tid & 63;
    const int l15 = lane & 15, l4 = lane >> 4;

    const int orig = blockIdx.x;
    const int blk = (orig & 7) * 64 + (orig >> 3);  // XCD-chunked, bijective (512%8==0)
    const int b = blk >> 4;
    const int t = blk & 15;
    const int qt = (t & 1) ? (t >> 1) : (15 - (t >> 1));  // heavy+light pairing
    const int q0 = qt * 64;

    // Q fragments (B-operand layout == A-layout read): held all loop
    const unsigned short* qp = qg + ((size_t)(b * SEQ + q0 + w * 16 + l15)) * DIM + l4 * 8;
    const bf16x8 qf0 = *(const bf16x8*)qp;
    const bf16x8 qf1 = *(const bf16x8*)(qp + 32);

    // staging addresses: thread -> (row sr, col sc)
    const int sr = tid >> 2, sc = (tid & 3) * 16;
    const unsigned short* kbase = kg + (size_t)b * SEQ * DIM + (size_t)sr * DIM + sc;
    const unsigned short* vbase = vtg + ((size_t)b * 64 + sr) * SEQ + sc;

    // prologue: stage tile 0 into buffer 0
    bf16x8 rk0 = *(const bf16x8*)(kbase);
    bf16x8 rk1 = *(const bf16x8*)(kbase + 8);
    bf16x8 rv0 = *(const bf16x8*)(vbase);
    bf16x8 rv1 = *(const bf16x8*)(vbase + 8);
    *(bf16x8*)&Ks[0][sr * LDP + sc]     = rk0;
    *(bf16x8*)&Ks[0][sr * LDP + sc + 8] = rk1;
    *(bf16x8*)&Vs[0][sr * LDP + sc]     = rv0;
    *(bf16x8*)&Vs[0][sr * LDP + sc + 8] = rv1;
    __syncthreads();

    f32x4 acc[4] = {};
    float m_run = -1e30f, l_run = 0.f;

    const int ntiles = qt + 1;
    for (int tt = 0; tt < ntiles; ++tt) {
        const int cur = tt & 1;
        const bool pf = (tt + 1 < ntiles);
        if (pf) {  // issue next-tile loads early: latency hides under compute
            const size_t kn = (size_t)(tt + 1) * 64;
            rk0 = *(const bf16x8*)(kbase + kn * DIM);
            rk1 = *(const bf16x8*)(kbase + kn * DIM + 8);
            rv0 = *(const bf16x8*)(vbase + kn);
            rv1 = *(const bf16x8*)(vbase + kn + 8);
        }

        // S^T = K . Q : lane holds S[k = nb*16+l4*4+r][q = l15]
        f32x4 s[4];
        __builtin_amdgcn_s_setprio(1);
        #pragma unroll
        for (int nb = 0; nb < 4; ++nb) {
            const bf16x8 kf0 = *(const bf16x8*)&Ks[cur][(nb * 16 + l15) * LDP + l4 * 8];
            const bf16x8 kf1 = *(const bf16x8*)&Ks[cur][(nb * 16 + l15) * LDP + 32 + l4 * 8];
            f32x4 sv = {0.f, 0.f, 0.f, 0.f};
            sv = MFMA16(kf0, qf0, sv, 0, 0, 0);
            sv = MFMA16(kf1, qf1, sv, 0, 0, 0);
            s[nb] = sv;
        }
        __builtin_amdgcn_s_setprio(0);

        if (tt == qt) {  // causal mask on diagonal tile
            const int qabs = q0 + w * 16 + l15;
            #pragma unroll
            for (int nb = 0; nb < 4; ++nb)
                #pragma unroll
                for (int r = 0; r < 4; ++r) {
                    const int kabs = tt * 64 + nb * 16 + l4 * 4 + r;
                    if (kabs > qabs) s[nb][r] = -1e30f;
                }
        }

        // softmax for q-row l15: 16 in-lane values + 2-shfl butterfly over l4
        float pmax = s[0][0];
        #pragma unroll
        for (int nb = 0; nb < 4; ++nb)
            #pragma unroll
            for (int r = 0; r < 4; ++r) pmax = fmaxf(pmax, s[nb][r]);
        pmax = fmaxf(pmax, __shfl_xor(pmax, 16));
        pmax = fmaxf(pmax, __shfl_xor(pmax, 32));

        const float mnew = fmaxf(m_run, pmax);
        const float sc_f = __expf(m_run - mnew);
        m_run = mnew;

        float psum = 0.f;
        #pragma unroll
        for (int nb = 0; nb < 4; ++nb)
            #pragma unroll
            for (int r = 0; r < 4; ++r) {
                s[nb][r] = __expf(s[nb][r] - mnew);
                psum += s[nb][r];
            }
        psum += __shfl_xor(psum, 16);
        psum += __shfl_xor(psum, 32);
        l_run = l_run * sc_f + psum;

        // rescale acc (acc row r holds q-row l4*4+r): broadcast that row's scale
        #pragma unroll
        for (int r = 0; r < 4; ++r) {
            const float srw = __shfl(sc_f, l4 * 4 + r);
            acc[0][r] *= srw; acc[1][r] *= srw; acc[2][r] *= srw; acc[3][r] *= srw;
        }

        // P -> LDS: 4 packed b64 writes (k contiguous), then A-frag readback
        #pragma unroll
        for (int nb = 0; nb < 4; ++nb) {
            const unsigned long long v =
                (unsigned long long)pk2(s[nb][0], s[nb][1]) |
                ((unsigned long long)pk2(s[nb][2], s[nb][3]) << 32);
            *(unsigned long long*)&Ps[w][l15 * LDP + nb * 16 + l4 * 4] = v;
        }
        const bf16x8 pa0 = *(const bf16x8*)&Ps[w][l15 * LDP + l4 * 8];
        const bf16x8 pa1 = *(const bf16x8*)&Ps[w][l15 * LDP + 32 + l4 * 8];

        __builtin_amdgcn_s_setprio(1);
        #pragma unroll
        for (int nb = 0; nb < 4; ++nb) {
            const bf16x8 vb0 = *(const bf16x8*)&Vs[cur][(nb * 16 + l15) * LDP + l4 * 8];
            const bf16x8 vb1 = *(const bf16x8*)&Vs[cur][(nb * 16 + l15) * LDP + 32 + l4 * 8];
            acc[nb] = MFMA16(pa0, vb0, acc[nb], 0, 0, 0);
            acc[nb] = MFMA16(pa1, vb1, acc[nb], 0, 0, 0);
        }
        __builtin_amdgcn_s_setprio(0);

        if (pf) {  // write staged regs into the other buffer (read last-1 iter)
            *(bf16x8*)&Ks[cur ^ 1][sr * LDP + sc]     = rk0;
            *(bf16x8*)&Ks[cur ^ 1][sr * LDP + sc + 8] = rk1;
            *(bf16x8*)&Vs[cur ^ 1][sr * LDP + sc]     = rv0;
            *(bf16x8*)&Vs[cur ^ 1][sr * LDP + sc + 8] = rv1;
        }
        __syncthreads();  // single barrier per tile
    }

    const float inv = 1.0f / l_run;
    #pragma unroll
    for (int r = 0; r < 4; ++r) {
        const float ir = __shfl(inv, l4 * 4 + r);
        const size_t row = (size_t)(b * SEQ + q0 + w * 16 + l4 * 4 + r);
        #pragma unroll
        for (int nb = 0; nb < 4; ++nb)
            out[row * DIM + nb * 16 + l15] = acc[nb][r] * ir;
    }
}

extern "C" void kernel_launch(void* const* d_in, const int* in_sizes, int n_in,
                              void* d_out, int out_size, void* d_ws, size_t ws_size,
                              hipStream_t stream) {
    const float* x  = (const float*)d_in[0];
    const float* Wq = (const float*)d_in[1];
    const float* Wk = (const float*)d_in[2];
    const float* Wv = (const float*)d_in[3];
    float* outp = (float*)d_out;

    unsigned short* qw  = (unsigned short*)d_ws;
    unsigned short* kw  = qw + (size_t)NB * SEQ * DIM;
    unsigned short* vtw = kw + (size_t)NB * SEQ * DIM;

    qkv_proj<<<NB * SEQ / 64, 256, 0, stream>>>(x, Wq, Wk, Wv, qw, kw, vtw);
    attn<<<NB * (SEQ / 64), 256, 0, stream>>>(qw, kw, vtw, outp);
}